// Round 7
// baseline (280.170 us; speedup 1.0000x reference)
//
#include <hip/hip_runtime.h>
#include <hip/hip_fp16.h>

#define DIMX 4096
#define NB   32
#define NQH  32
#define NKVH 8
#define HDIM 128
#define SEQ  2048
#define CHUNK  128   // positions per attention block
#define NCHUNK 16    // 2048/128

typedef float vfloat2 __attribute__((ext_vector_type(2)));

__device__ __forceinline__ vfloat2 ntload2(const float* p) {
  return __builtin_nontemporal_load(reinterpret_cast<const vfloat2*>(p));
}

// ---------------- Kernel 1: QKV partial GEMM (fp16 partials) ----------------
// grid (12, 32): 12 col-chunks of 512 (2 ADJACENT cols/thread), 32 d-chunks of 128
__global__ __launch_bounds__(256) void k_qkv(const float* __restrict__ x,
                                             const float* __restrict__ wq,
                                             const float* __restrict__ wk,
                                             const float* __restrict__ wv,
                                             __half2* __restrict__ partial) {
  __shared__ float xs[32][132];
  const int t = threadIdx.x;
  const int d0 = blockIdx.y * 128;
  for (int e = t; e < 32 * 32; e += 256) {
    const int b = e >> 5, q = e & 31;
    *reinterpret_cast<float4*>(&xs[b][q * 4]) =
        *reinterpret_cast<const float4*>(&x[b * DIMX + d0 + q * 4]);
  }
  __syncthreads();
  const int base = blockIdx.x * 512;
  const float* W; int ncols, lbase;
  if (base < 4096)      { W = wq; ncols = 4096; lbase = base; }
  else if (base < 5120) { W = wk; ncols = 1024; lbase = base - 4096; }
  else                  { W = wv; ncols = 1024; lbase = base - 5120; }
  const float* Wp = W + (size_t)d0 * ncols + lbase + 2 * t;
  float accA[32], accB[32];
  #pragma unroll
  for (int b = 0; b < 32; ++b) { accA[b] = 0.f; accB[b] = 0.f; }
  for (int dd = 0; dd < 128; dd += 4) {
    const vfloat2 w0 = ntload2(&Wp[(size_t)(dd + 0) * ncols]);
    const vfloat2 w1 = ntload2(&Wp[(size_t)(dd + 1) * ncols]);
    const vfloat2 w2 = ntload2(&Wp[(size_t)(dd + 2) * ncols]);
    const vfloat2 w3 = ntload2(&Wp[(size_t)(dd + 3) * ncols]);
    #pragma unroll
    for (int b = 0; b < 32; ++b) {
      const float4 xv = *reinterpret_cast<const float4*>(&xs[b][dd]);
      accA[b] += xv.x * w0.x + xv.y * w1.x + xv.z * w2.x + xv.w * w3.x;
      accB[b] += xv.x * w0.y + xv.y * w1.y + xv.z * w2.y + xv.w * w3.y;
    }
  }
  #pragma unroll
  for (int b = 0; b < 32; ++b)
    partial[((size_t)blockIdx.y * 32 + b) * 3072 + (base >> 1) + t] =
        __floats2half2_rn(accA[b], accB[b]);
}

// ---------------- Kernel 2: combine fp16 partials + RoPE ----------------
// one thread per (b, column-quad); 32*1536 quads / 256 = 192 blocks
__global__ __launch_bounds__(256) void k_combine_rope(const __half2* __restrict__ partial,
                                                      const float* __restrict__ fr,
                                                      const float* __restrict__ fi,
                                                      float* __restrict__ qkv) {
  const int p = blockIdx.x * 256 + threadIdx.x;
  const int b = p / 1536, cq = p % 1536;
  const int col = cq * 4;
  float sx = 0.f, sy = 0.f, sz = 0.f, sw = 0.f;
  for (int c = 0; c < 32; ++c) {
    const size_t idx = ((size_t)c * 32 + b) * 3072 + cq * 2;
    const float2 f01 = __half22float2(partial[idx]);
    const float2 f23 = __half22float2(partial[idx + 1]);
    sx += f01.x; sy += f01.y; sz += f23.x; sw += f23.y;
  }
  if (col < 5120) {
    const int i = (col & 127) >> 1;
    const float cr0 = fr[i],     ci0 = fi[i];
    const float cr1 = fr[i + 1], ci1 = fi[i + 1];
    const float o0 = sx * cr0 - sy * ci0;
    const float o1 = sx * ci0 + sy * cr0;
    const float o2 = sz * cr1 - sw * ci1;
    const float o3 = sz * ci1 + sw * cr1;
    sx = o0; sy = o1; sz = o2; sw = o3;
  }
  *reinterpret_cast<float4*>(&qkv[(size_t)b * 6144 + col]) = make_float4(sx, sy, sz, sw);
}

// ---------------- Kernel 3: flash-decoding attention ----------------
// grid = 512 (32 b x 16 chunks of 128 pos), 512 threads = 8 waves, wave = g.
// At the measured platform read ceiling (~3 TB/s); opart stored fp16.
__global__ __launch_bounds__(512) void k_attn(const float* __restrict__ qkv,
                                              const float* __restrict__ cache_k,
                                              const float* __restrict__ cache_v,
                                              __half2* __restrict__ opart,
                                              float* __restrict__ ml) {
  __shared__ float qls[4096];          // [g][rep][128] = 16 KB
  __shared__ float ps[8 * 128 * 4];    // [g][j][rep]   = 16 KB
  const int bx = blockIdx.x;
  const int c = bx & 15, b = bx >> 4;
  const int t = threadIdx.x;
  const int g = t >> 6, lane = t & 63;

  {
    const float4* src = reinterpret_cast<const float4*>(&qkv[(size_t)b * 6144]);
    float4* dst = reinterpret_cast<float4*>(qls);
    for (int e = t; e < 1024; e += 512) dst[e] = src[e];
  }
  __syncthreads();

  const int j0 = c * CHUNK;
  const int jA = j0 + lane;            // <= 1983, never the new token
  const int jB = j0 + 64 + lane;       // == 2047 only when c==15 && lane==63
  const float* krowA = &cache_k[(((size_t)b * SEQ + jA) * NKVH + g) * HDIM];
  const float* krowB = (jB == 2047) ? &qkv[(size_t)b * 6144 + 4096 + g * 128]
                                    : &cache_k[(((size_t)b * SEQ + jB) * NKVH + g) * HDIM];
  const float4* krA4 = reinterpret_cast<const float4*>(krowA);
  const float4* krB4 = reinterpret_cast<const float4*>(krowB);
  const float4* q4g = reinterpret_cast<const float4*>(&qls[g * 512]);

  float sA0 = 0.f, sA1 = 0.f, sA2 = 0.f, sA3 = 0.f;
  float sB0 = 0.f, sB1 = 0.f, sB2 = 0.f, sB3 = 0.f;
  #pragma unroll 4
  for (int dq = 0; dq < 32; ++dq) {
    const float4 ka = krA4[dq];
    const float4 kb = krB4[dq];
    const float4 qa = q4g[dq];
    const float4 qb = q4g[32 + dq];
    const float4 qc = q4g[64 + dq];
    const float4 qd = q4g[96 + dq];
    sA0 += ka.x * qa.x + ka.y * qa.y + ka.z * qa.z + ka.w * qa.w;
    sA1 += ka.x * qb.x + ka.y * qb.y + ka.z * qb.z + ka.w * qb.w;
    sA2 += ka.x * qc.x + ka.y * qc.y + ka.z * qc.z + ka.w * qc.w;
    sA3 += ka.x * qd.x + ka.y * qd.y + ka.z * qd.z + ka.w * qd.w;
    sB0 += kb.x * qa.x + kb.y * qa.y + kb.z * qa.z + kb.w * qa.w;
    sB1 += kb.x * qb.x + kb.y * qb.y + kb.z * qb.z + kb.w * qb.w;
    sB2 += kb.x * qc.x + kb.y * qc.y + kb.z * qc.z + kb.w * qc.w;
    sB3 += kb.x * qd.x + kb.y * qd.y + kb.z * qd.z + kb.w * qd.w;
  }
  const float sc = 0.08838834764831845f;  // 1/sqrt(128)
  sA0 *= sc; sA1 *= sc; sA2 *= sc; sA3 *= sc;
  sB0 *= sc; sB1 *= sc; sB2 *= sc; sB3 *= sc;

  float m0 = fmaxf(sA0, sB0), m1 = fmaxf(sA1, sB1);
  float m2 = fmaxf(sA2, sB2), m3 = fmaxf(sA3, sB3);
  #pragma unroll
  for (int o = 32; o > 0; o >>= 1) {
    m0 = fmaxf(m0, __shfl_xor(m0, o));
    m1 = fmaxf(m1, __shfl_xor(m1, o));
    m2 = fmaxf(m2, __shfl_xor(m2, o));
    m3 = fmaxf(m3, __shfl_xor(m3, o));
  }
  const float pA0 = __expf(sA0 - m0), pA1 = __expf(sA1 - m1);
  const float pA2 = __expf(sA2 - m2), pA3 = __expf(sA3 - m3);
  const float pB0 = __expf(sB0 - m0), pB1 = __expf(sB1 - m1);
  const float pB2 = __expf(sB2 - m2), pB3 = __expf(sB3 - m3);
  float l0 = pA0 + pB0, l1 = pA1 + pB1, l2 = pA2 + pB2, l3 = pA3 + pB3;
  #pragma unroll
  for (int o = 32; o > 0; o >>= 1) {
    l0 += __shfl_xor(l0, o);
    l1 += __shfl_xor(l1, o);
    l2 += __shfl_xor(l2, o);
    l3 += __shfl_xor(l3, o);
  }
  float4* ps4g = reinterpret_cast<float4*>(ps) + g * 128;
  ps4g[lane]      = make_float4(pA0, pA1, pA2, pA3);
  ps4g[64 + lane] = make_float4(pB0, pB1, pB2, pB3);
  __syncthreads();

  // PV: lane = dim-pair; V rows contiguous across the block's 8 waves.
  float a00 = 0.f, a01 = 0.f, a10 = 0.f, a11 = 0.f;
  float a20 = 0.f, a21 = 0.f, a30 = 0.f, a31 = 0.f;
  const float4* psg = reinterpret_cast<const float4*>(ps) + g * 128;
  const float* vbase = &cache_v[(((size_t)b * SEQ + j0) * NKVH + g) * HDIM];
  const float* vlast = &qkv[(size_t)b * 6144 + 5120 + g * 128];
  #pragma unroll 8
  for (int jj = 0; jj < CHUNK; ++jj) {
    const float4 p4 = psg[jj];
    vfloat2 v2;
    if (j0 + jj == 2047) {
      const float2 tmp = *reinterpret_cast<const float2*>(&vlast[lane * 2]);
      v2.x = tmp.x; v2.y = tmp.y;
    } else {
      v2 = ntload2(&vbase[(size_t)jj * (NKVH * HDIM) + lane * 2]);
    }
    a00 += p4.x * v2.x; a01 += p4.x * v2.y;
    a10 += p4.y * v2.x; a11 += p4.y * v2.y;
    a20 += p4.z * v2.x; a21 += p4.z * v2.y;
    a30 += p4.w * v2.x; a31 += p4.w * v2.y;
  }
  const int bg = b * NKVH + g;
  opart[(((size_t)(bg * 4 + 0)) * NCHUNK + c) * 64 + lane] = __floats2half2_rn(a00, a01);
  opart[(((size_t)(bg * 4 + 1)) * NCHUNK + c) * 64 + lane] = __floats2half2_rn(a10, a11);
  opart[(((size_t)(bg * 4 + 2)) * NCHUNK + c) * 64 + lane] = __floats2half2_rn(a20, a21);
  opart[(((size_t)(bg * 4 + 3)) * NCHUNK + c) * 64 + lane] = __floats2half2_rn(a30, a31);
  if (lane == 0) {
    ml[(((size_t)(bg * 4 + 0)) * NCHUNK + c) * 2]     = m0;
    ml[(((size_t)(bg * 4 + 0)) * NCHUNK + c) * 2 + 1] = l0;
    ml[(((size_t)(bg * 4 + 1)) * NCHUNK + c) * 2]     = m1;
    ml[(((size_t)(bg * 4 + 1)) * NCHUNK + c) * 2 + 1] = l1;
    ml[(((size_t)(bg * 4 + 2)) * NCHUNK + c) * 2]     = m2;
    ml[(((size_t)(bg * 4 + 2)) * NCHUNK + c) * 2 + 1] = l2;
    ml[(((size_t)(bg * 4 + 3)) * NCHUNK + c) * 2]     = m3;
    ml[(((size_t)(bg * 4 + 3)) * NCHUNK + c) * 2 + 1] = l3;
  }
}

// ---------------- Kernel 4: combine chunk partials (fp16 opart) ----------------
__global__ __launch_bounds__(128) void k_attn_combine(const __half* __restrict__ opart,
                                                      const float* __restrict__ ml,
                                                      float* __restrict__ attn_out) {
  const int bgr = blockIdx.x;
  const int d = threadIdx.x;
  float M = -1e30f;
  for (int c = 0; c < NCHUNK; ++c) M = fmaxf(M, ml[((size_t)bgr * NCHUNK + c) * 2]);
  float L = 0.f, acc = 0.f;
  for (int c = 0; c < NCHUNK; ++c) {
    const float w = __expf(ml[((size_t)bgr * NCHUNK + c) * 2] - M);
    L += ml[((size_t)bgr * NCHUNK + c) * 2 + 1] * w;
    acc += __half2float(opart[((size_t)bgr * NCHUNK + c) * 128 + d]) * w;
  }
  attn_out[(size_t)bgr * 128 + d] = acc / L;
}

// ---------------- Kernel 5: output projection partial GEMM (fp16 partials) ----------------
// grid (8, 32): 8 col-chunks of 512 (2 ADJACENT cols/thread), 32 d-chunks of 128
__global__ __launch_bounds__(256) void k_oproj(const float* __restrict__ attn_out,
                                               const float* __restrict__ wo,
                                               __half2* __restrict__ partial) {
  __shared__ float xs[32][132];
  const int t = threadIdx.x;
  const int d0 = blockIdx.y * 128;
  for (int e = t; e < 32 * 32; e += 256) {
    const int b = e >> 5, q = e & 31;
    *reinterpret_cast<float4*>(&xs[b][q * 4]) =
        *reinterpret_cast<const float4*>(&attn_out[b * DIMX + d0 + q * 4]);
  }
  __syncthreads();
  const int base = blockIdx.x * 512;
  const float* Wp = wo + (size_t)d0 * 4096 + base + 2 * t;
  float accA[32], accB[32];
  #pragma unroll
  for (int b = 0; b < 32; ++b) { accA[b] = 0.f; accB[b] = 0.f; }
  for (int dd = 0; dd < 128; dd += 4) {
    const vfloat2 w0 = ntload2(&Wp[(size_t)(dd + 0) * 4096]);
    const vfloat2 w1 = ntload2(&Wp[(size_t)(dd + 1) * 4096]);
    const vfloat2 w2 = ntload2(&Wp[(size_t)(dd + 2) * 4096]);
    const vfloat2 w3 = ntload2(&Wp[(size_t)(dd + 3) * 4096]);
    #pragma unroll
    for (int b = 0; b < 32; ++b) {
      const float4 xv = *reinterpret_cast<const float4*>(&xs[b][dd]);
      accA[b] += xv.x * w0.x + xv.y * w1.x + xv.z * w2.x + xv.w * w3.x;
      accB[b] += xv.x * w0.y + xv.y * w1.y + xv.z * w2.y + xv.w * w3.y;
    }
  }
  #pragma unroll
  for (int b = 0; b < 32; ++b)
    partial[((size_t)blockIdx.y * 32 + b) * 2048 + (base >> 1) + t] =
        __floats2half2_rn(accA[b], accB[b]);
}

// ---------------- Kernel 6: final combine (fp16 partials) ----------------
// 256 blocks x 256 threads, one thread per column-PAIR (65536 pairs)
__global__ __launch_bounds__(256) void k_final(const __half2* __restrict__ partial,
                                               float* __restrict__ out) {
  const int e2 = blockIdx.x * 256 + threadIdx.x;   // pair id
  const int b = e2 >> 11, cp = e2 & 2047;
  float s0 = 0.f, s1 = 0.f;
  for (int c = 0; c < 32; ++c) {
    const float2 f = __half22float2(partial[((size_t)c * 32 + b) * 2048 + cp]);
    s0 += f.x; s1 += f.y;
  }
  *reinterpret_cast<float2*>(&out[(size_t)b * 4096 + cp * 2]) = make_float2(s0, s1);
}

extern "C" void kernel_launch(void* const* d_in, const int* in_sizes, int n_in,
                              void* d_out, int out_size, void* d_ws, size_t ws_size,
                              hipStream_t stream) {
  const float* x  = (const float*)d_in[0];
  const float* fr = (const float*)d_in[2];
  const float* fi = (const float*)d_in[3];
  const float* wq = (const float*)d_in[4];
  const float* wk = (const float*)d_in[5];
  const float* wv = (const float*)d_in[6];
  const float* wo = (const float*)d_in[7];
  const float* ck = (const float*)d_in[8];
  const float* cv = (const float*)d_in[9];
  float* out = (float*)d_out;

  float* ws = (float*)d_ws;
  // big region (aliased, disjoint lifetimes), all fp16 now:
  //   qkv_partial 32*32*6144 halves = 12.6 MB | opart 1024*16*128 halves = 4.2 MB
  //   out_partial 32*32*4096 halves = 8.4 MB
  __half2* big_h2 = (__half2*)ws;        // 3,145,728 floats reserved
  float* qkv  = ws + 3145728;            //   196,608
  float* mlb  = ws + 3342336;            //    32,768 (1024*16*2)
  float* attn = ws + 3375104;            //   131,072
  // total 3,506,176 floats = 14.0 MiB

  k_qkv<<<dim3(12, 32), 256, 0, stream>>>(x, wq, wk, wv, big_h2);
  k_combine_rope<<<192, 256, 0, stream>>>(big_h2, fr, fi, qkv);
  k_attn<<<32 * NCHUNK, 512, 0, stream>>>(qkv, ck, cv, big_h2, mlb);
  k_attn_combine<<<1024, 128, 0, stream>>>((const __half*)big_h2, mlb, attn);
  k_oproj<<<dim3(8, 32), 256, 0, stream>>>(attn, wo, big_h2);
  k_final<<<256, 256, 0, stream>>>(big_h2, out);
}

// Round 8
// 266.725 us; speedup vs baseline: 1.0504x; 1.0504x over previous
//
#include <hip/hip_runtime.h>

#define DIMX 4096
#define NB   32
#define NQH  32
#define NKVH 8
#define HDIM 128
#define SEQ  2048
#define CHUNK  128   // positions per attention block
#define NCHUNK 16    // 2048/128

typedef float vfloat2 __attribute__((ext_vector_type(2)));

__device__ __forceinline__ float ntloadf(const float* p) {
  return __builtin_nontemporal_load(p);
}
__device__ __forceinline__ vfloat2 ntload2(const float* p) {
  return __builtin_nontemporal_load(reinterpret_cast<const vfloat2*>(p));
}

// ---------------- Kernel 1: QKV partial GEMM ----------------
// grid (12, 32): 12 col-chunks of 512 (2 cols/thread), 32 d-chunks of 128
__global__ __launch_bounds__(256) void k_qkv(const float* __restrict__ x,
                                             const float* __restrict__ wq,
                                             const float* __restrict__ wk,
                                             const float* __restrict__ wv,
                                             float* __restrict__ partial) {
  __shared__ float xs[32][132];
  const int t = threadIdx.x;
  const int d0 = blockIdx.y * 128;
  for (int e = t; e < 32 * 32; e += 256) {
    const int b = e >> 5, q = e & 31;
    *reinterpret_cast<float4*>(&xs[b][q * 4]) =
        *reinterpret_cast<const float4*>(&x[b * DIMX + d0 + q * 4]);
  }
  __syncthreads();
  const int base = blockIdx.x * 512;
  const float* W; int ncols, lbase;
  if (base < 4096)      { W = wq; ncols = 4096; lbase = base; }
  else if (base < 5120) { W = wk; ncols = 1024; lbase = base - 4096; }
  else                  { W = wv; ncols = 1024; lbase = base - 5120; }
  const float* WA = W + (size_t)d0 * ncols + lbase + t;
  const float* WB = WA + 256;
  float accA[32], accB[32];
  #pragma unroll
  for (int b = 0; b < 32; ++b) { accA[b] = 0.f; accB[b] = 0.f; }
  for (int dd = 0; dd < 128; dd += 4) {
    const float a0 = ntloadf(&WA[(size_t)(dd + 0) * ncols]);
    const float a1 = ntloadf(&WA[(size_t)(dd + 1) * ncols]);
    const float a2 = ntloadf(&WA[(size_t)(dd + 2) * ncols]);
    const float a3 = ntloadf(&WA[(size_t)(dd + 3) * ncols]);
    const float b0 = ntloadf(&WB[(size_t)(dd + 0) * ncols]);
    const float b1 = ntloadf(&WB[(size_t)(dd + 1) * ncols]);
    const float b2 = ntloadf(&WB[(size_t)(dd + 2) * ncols]);
    const float b3 = ntloadf(&WB[(size_t)(dd + 3) * ncols]);
    #pragma unroll
    for (int b = 0; b < 32; ++b) {
      const float4 xv = *reinterpret_cast<const float4*>(&xs[b][dd]);
      accA[b] += xv.x * a0 + xv.y * a1 + xv.z * a2 + xv.w * a3;
      accB[b] += xv.x * b0 + xv.y * b1 + xv.z * b2 + xv.w * b3;
    }
  }
  #pragma unroll
  for (int b = 0; b < 32; ++b) {
    partial[((size_t)blockIdx.y * 32 + b) * 6144 + base + t]       = accA[b];
    partial[((size_t)blockIdx.y * 32 + b) * 6144 + base + 256 + t] = accB[b];
  }
}

// ---------------- Kernel 2: combine partials + RoPE ----------------
__global__ __launch_bounds__(256) void k_combine_rope(const float* __restrict__ partial,
                                                      const float* __restrict__ fr,
                                                      const float* __restrict__ fi,
                                                      float* __restrict__ qkv) {
  const int p = blockIdx.x * 256 + threadIdx.x;
  const int b = p / 1536, cq = p % 1536;
  const int col = cq * 4;
  float sx = 0.f, sy = 0.f, sz = 0.f, sw = 0.f;
  for (int c = 0; c < 32; ++c) {
    const float4 v = *reinterpret_cast<const float4*>(&partial[((size_t)c * 32 + b) * 6144 + col]);
    sx += v.x; sy += v.y; sz += v.z; sw += v.w;
  }
  if (col < 5120) {
    const int i = (col & 127) >> 1;
    const float cr0 = fr[i],     ci0 = fi[i];
    const float cr1 = fr[i + 1], ci1 = fi[i + 1];
    const float o0 = sx * cr0 - sy * ci0;
    const float o1 = sx * ci0 + sy * cr0;
    const float o2 = sz * cr1 - sw * ci1;
    const float o3 = sz * ci1 + sw * cr1;
    sx = o0; sy = o1; sz = o2; sw = o3;
  }
  *reinterpret_cast<float4*>(&qkv[(size_t)b * 6144 + col]) = make_float4(sx, sy, sz, sw);
}

// ---------------- Kernel 3: flash-decoding attention ----------------
// grid = 512 (32 b x 16 chunks of 128 pos), 512 threads = 8 waves, wave = g.
// V loads are NONTEMPORAL (single-touch lines); K stays cached (each lane
// revisits its row's 128B lines across 8 dq iterations). At the measured
// platform read ceiling (~3.05 TB/s effective).
__global__ __launch_bounds__(512) void k_attn(const float* __restrict__ qkv,
                                              const float* __restrict__ cache_k,
                                              const float* __restrict__ cache_v,
                                              float* __restrict__ opart,
                                              float* __restrict__ ml) {
  __shared__ float qls[4096];          // [g][rep][128] = 16 KB
  __shared__ float ps[8 * 128 * 4];    // [g][j][rep]   = 16 KB
  const int bx = blockIdx.x;
  const int c = bx & 15, b = bx >> 4;
  const int t = threadIdx.x;
  const int g = t >> 6, lane = t & 63;

  {
    const float4* src = reinterpret_cast<const float4*>(&qkv[(size_t)b * 6144]);
    float4* dst = reinterpret_cast<float4*>(qls);
    for (int e = t; e < 1024; e += 512) dst[e] = src[e];
  }
  __syncthreads();

  const int j0 = c * CHUNK;
  const int jA = j0 + lane;            // <= 1983, never the new token
  const int jB = j0 + 64 + lane;       // == 2047 only when c==15 && lane==63
  const float* krowA = &cache_k[(((size_t)b * SEQ + jA) * NKVH + g) * HDIM];
  const float* krowB = (jB == 2047) ? &qkv[(size_t)b * 6144 + 4096 + g * 128]
                                    : &cache_k[(((size_t)b * SEQ + jB) * NKVH + g) * HDIM];
  const float4* krA4 = reinterpret_cast<const float4*>(krowA);
  const float4* krB4 = reinterpret_cast<const float4*>(krowB);
  const float4* q4g = reinterpret_cast<const float4*>(&qls[g * 512]);

  float sA0 = 0.f, sA1 = 0.f, sA2 = 0.f, sA3 = 0.f;
  float sB0 = 0.f, sB1 = 0.f, sB2 = 0.f, sB3 = 0.f;
  #pragma unroll 4
  for (int dq = 0; dq < 32; ++dq) {
    const float4 ka = krA4[dq];
    const float4 kb = krB4[dq];
    const float4 qa = q4g[dq];
    const float4 qb = q4g[32 + dq];
    const float4 qc = q4g[64 + dq];
    const float4 qd = q4g[96 + dq];
    sA0 += ka.x * qa.x + ka.y * qa.y + ka.z * qa.z + ka.w * qa.w;
    sA1 += ka.x * qb.x + ka.y * qb.y + ka.z * qb.z + ka.w * qb.w;
    sA2 += ka.x * qc.x + ka.y * qc.y + ka.z * qc.z + ka.w * qc.w;
    sA3 += ka.x * qd.x + ka.y * qd.y + ka.z * qd.z + ka.w * qd.w;
    sB0 += kb.x * qa.x + kb.y * qa.y + kb.z * qa.z + kb.w * qa.w;
    sB1 += kb.x * qb.x + kb.y * qb.y + kb.z * qb.z + kb.w * qb.w;
    sB2 += kb.x * qc.x + kb.y * qc.y + kb.z * qc.z + kb.w * qc.w;
    sB3 += kb.x * qd.x + kb.y * qd.y + kb.z * qd.z + kb.w * qd.w;
  }
  const float sc = 0.08838834764831845f;  // 1/sqrt(128)
  sA0 *= sc; sA1 *= sc; sA2 *= sc; sA3 *= sc;
  sB0 *= sc; sB1 *= sc; sB2 *= sc; sB3 *= sc;

  float m0 = fmaxf(sA0, sB0), m1 = fmaxf(sA1, sB1);
  float m2 = fmaxf(sA2, sB2), m3 = fmaxf(sA3, sB3);
  #pragma unroll
  for (int o = 32; o > 0; o >>= 1) {
    m0 = fmaxf(m0, __shfl_xor(m0, o));
    m1 = fmaxf(m1, __shfl_xor(m1, o));
    m2 = fmaxf(m2, __shfl_xor(m2, o));
    m3 = fmaxf(m3, __shfl_xor(m3, o));
  }
  const float pA0 = __expf(sA0 - m0), pA1 = __expf(sA1 - m1);
  const float pA2 = __expf(sA2 - m2), pA3 = __expf(sA3 - m3);
  const float pB0 = __expf(sB0 - m0), pB1 = __expf(sB1 - m1);
  const float pB2 = __expf(sB2 - m2), pB3 = __expf(sB3 - m3);
  float l0 = pA0 + pB0, l1 = pA1 + pB1, l2 = pA2 + pB2, l3 = pA3 + pB3;
  #pragma unroll
  for (int o = 32; o > 0; o >>= 1) {
    l0 += __shfl_xor(l0, o);
    l1 += __shfl_xor(l1, o);
    l2 += __shfl_xor(l2, o);
    l3 += __shfl_xor(l3, o);
  }
  float4* ps4g = reinterpret_cast<float4*>(ps) + g * 128;
  ps4g[lane]      = make_float4(pA0, pA1, pA2, pA3);
  ps4g[64 + lane] = make_float4(pB0, pB1, pB2, pB3);
  __syncthreads();

  // PV: lane = dim-pair; V rows contiguous across the block's 8 waves.
  float a00 = 0.f, a01 = 0.f, a10 = 0.f, a11 = 0.f;
  float a20 = 0.f, a21 = 0.f, a30 = 0.f, a31 = 0.f;
  const float4* psg = reinterpret_cast<const float4*>(ps) + g * 128;
  const float* vbase = &cache_v[(((size_t)b * SEQ + j0) * NKVH + g) * HDIM];
  const float* vlast = &qkv[(size_t)b * 6144 + 5120 + g * 128];
  #pragma unroll 8
  for (int jj = 0; jj < CHUNK; ++jj) {
    const float4 p4 = psg[jj];
    vfloat2 v2;
    if (j0 + jj == 2047) {
      const float2 tmp = *reinterpret_cast<const float2*>(&vlast[lane * 2]);
      v2.x = tmp.x; v2.y = tmp.y;
    } else {
      v2 = ntload2(&vbase[(size_t)jj * (NKVH * HDIM) + lane * 2]);
    }
    a00 += p4.x * v2.x; a01 += p4.x * v2.y;
    a10 += p4.y * v2.x; a11 += p4.y * v2.y;
    a20 += p4.z * v2.x; a21 += p4.z * v2.y;
    a30 += p4.w * v2.x; a31 += p4.w * v2.y;
  }
  const int bg = b * NKVH + g;
  *reinterpret_cast<float2*>(&opart[(((size_t)(bg * 4 + 0)) * NCHUNK + c) * 128 + lane * 2]) = make_float2(a00, a01);
  *reinterpret_cast<float2*>(&opart[(((size_t)(bg * 4 + 1)) * NCHUNK + c) * 128 + lane * 2]) = make_float2(a10, a11);
  *reinterpret_cast<float2*>(&opart[(((size_t)(bg * 4 + 2)) * NCHUNK + c) * 128 + lane * 2]) = make_float2(a20, a21);
  *reinterpret_cast<float2*>(&opart[(((size_t)(bg * 4 + 3)) * NCHUNK + c) * 128 + lane * 2]) = make_float2(a30, a31);
  if (lane == 0) {
    ml[(((size_t)(bg * 4 + 0)) * NCHUNK + c) * 2]     = m0;
    ml[(((size_t)(bg * 4 + 0)) * NCHUNK + c) * 2 + 1] = l0;
    ml[(((size_t)(bg * 4 + 1)) * NCHUNK + c) * 2]     = m1;
    ml[(((size_t)(bg * 4 + 1)) * NCHUNK + c) * 2 + 1] = l1;
    ml[(((size_t)(bg * 4 + 2)) * NCHUNK + c) * 2]     = m2;
    ml[(((size_t)(bg * 4 + 2)) * NCHUNK + c) * 2 + 1] = l2;
    ml[(((size_t)(bg * 4 + 3)) * NCHUNK + c) * 2]     = m3;
    ml[(((size_t)(bg * 4 + 3)) * NCHUNK + c) * 2 + 1] = l3;
  }
}

// ---------------- Kernel 4: combine chunk partials ----------------
__global__ __launch_bounds__(128) void k_attn_combine(const float* __restrict__ opart,
                                                      const float* __restrict__ ml,
                                                      float* __restrict__ attn_out) {
  const int bgr = blockIdx.x;
  const int d = threadIdx.x;
  float M = -1e30f;
  for (int c = 0; c < NCHUNK; ++c) M = fmaxf(M, ml[((size_t)bgr * NCHUNK + c) * 2]);
  float L = 0.f, acc = 0.f;
  for (int c = 0; c < NCHUNK; ++c) {
    const float w = __expf(ml[((size_t)bgr * NCHUNK + c) * 2] - M);
    L += ml[((size_t)bgr * NCHUNK + c) * 2 + 1] * w;
    acc += opart[((size_t)bgr * NCHUNK + c) * 128 + d] * w;
  }
  attn_out[(size_t)bgr * 128 + d] = acc / L;
}

// ---------------- Kernel 5: output projection partial GEMM ----------------
__global__ __launch_bounds__(256) void k_oproj(const float* __restrict__ attn_out,
                                               const float* __restrict__ wo,
                                               float* __restrict__ partial) {
  __shared__ float xs[32][132];
  const int t = threadIdx.x;
  const int d0 = blockIdx.y * 128;
  for (int e = t; e < 32 * 32; e += 256) {
    const int b = e >> 5, q = e & 31;
    *reinterpret_cast<float4*>(&xs[b][q * 4]) =
        *reinterpret_cast<const float4*>(&attn_out[b * DIMX + d0 + q * 4]);
  }
  __syncthreads();
  const int base = blockIdx.x * 512;
  const float* WA = wo + (size_t)d0 * 4096 + base + t;
  const float* WB = WA + 256;
  float accA[32], accB[32];
  #pragma unroll
  for (int b = 0; b < 32; ++b) { accA[b] = 0.f; accB[b] = 0.f; }
  for (int dd = 0; dd < 128; dd += 4) {
    const float a0 = ntloadf(&WA[(size_t)(dd + 0) * 4096]);
    const float a1 = ntloadf(&WA[(size_t)(dd + 1) * 4096]);
    const float a2 = ntloadf(&WA[(size_t)(dd + 2) * 4096]);
    const float a3 = ntloadf(&WA[(size_t)(dd + 3) * 4096]);
    const float b0 = ntloadf(&WB[(size_t)(dd + 0) * 4096]);
    const float b1 = ntloadf(&WB[(size_t)(dd + 1) * 4096]);
    const float b2 = ntloadf(&WB[(size_t)(dd + 2) * 4096]);
    const float b3 = ntloadf(&WB[(size_t)(dd + 3) * 4096]);
    #pragma unroll
    for (int b = 0; b < 32; ++b) {
      const float4 xv = *reinterpret_cast<const float4*>(&xs[b][dd]);
      accA[b] += xv.x * a0 + xv.y * a1 + xv.z * a2 + xv.w * a3;
      accB[b] += xv.x * b0 + xv.y * b1 + xv.z * b2 + xv.w * b3;
    }
  }
  #pragma unroll
  for (int b = 0; b < 32; ++b) {
    partial[((size_t)blockIdx.y * 32 + b) * 4096 + base + t]       = accA[b];
    partial[((size_t)blockIdx.y * 32 + b) * 4096 + base + 256 + t] = accB[b];
  }
}

// ---------------- Kernel 6: final combine ----------------
__global__ __launch_bounds__(256) void k_final(const float* __restrict__ partial,
                                               float* __restrict__ out) {
  const int e = blockIdx.x * 256 + threadIdx.x;
  const int b = e >> 12, col = e & 4095;
  float s = 0.f;
  for (int c = 0; c < 32; ++c) s += partial[((size_t)c * 32 + b) * 4096 + col];
  out[e] = s;
}

extern "C" void kernel_launch(void* const* d_in, const int* in_sizes, int n_in,
                              void* d_out, int out_size, void* d_ws, size_t ws_size,
                              hipStream_t stream) {
  const float* x  = (const float*)d_in[0];
  const float* fr = (const float*)d_in[2];
  const float* fi = (const float*)d_in[3];
  const float* wq = (const float*)d_in[4];
  const float* wk = (const float*)d_in[5];
  const float* wv = (const float*)d_in[6];
  const float* wo = (const float*)d_in[7];
  const float* ck = (const float*)d_in[8];
  const float* cv = (const float*)d_in[9];
  float* out = (float*)d_out;

  float* ws = (float*)d_ws;
  // big region (aliased, disjoint lifetimes):
  //   qkv_partial 32*32*6144 = 6,291,456 | opart 1024*16*128 = 2,097,152
  //   out_partial 32*32*4096 = 4,194,304
  float* big  = ws;                 // 6,291,456 floats
  float* qkv  = ws + 6291456;       //   196,608
  float* mlb  = ws + 6488064;       //    32,768 (1024*16*2)
  float* attn = ws + 6553600;       //   131,072

  k_qkv<<<dim3(12, 32), 256, 0, stream>>>(x, wq, wk, wv, big);
  k_combine_rope<<<192, 256, 0, stream>>>(big, fr, fi, qkv);
  k_attn<<<32 * NCHUNK, 512, 0, stream>>>(qkv, ck, cv, big, mlb);
  k_attn_combine<<<1024, 128, 0, stream>>>(big, mlb, attn);
  k_oproj<<<dim3(8, 32), 256, 0, stream>>>(attn, wo, big);
  k_final<<<512, 256, 0, stream>>>(big, out);
}